// Round 3
// baseline (313.731 us; speedup 1.0000x reference)
//
#include <hip/hip_runtime.h>
#include <hip/hip_bf16.h>
#include <cstdint>

#define TOKENS 2048
#define Dm 1024
#define Fm 4096
#define Em 8

typedef short s16x8 __attribute__((ext_vector_type(8)));
typedef float f32x4 __attribute__((ext_vector_type(4)));

#define GLOAD16(g, l) __builtin_amdgcn_global_load_lds(                     \
    (const __attribute__((address_space(1))) void*)(g),                     \
    (__attribute__((address_space(3))) void*)(l), 16, 0, 0)

__device__ __forceinline__ ushort f2bf(float f) {
  union { float f; uint32_t u; } v; v.f = f;
  uint32_t r = v.u + 0x7fffu + ((v.u >> 16) & 1u);
  return (ushort)(r >> 16);
}

// ------------- standalone transpose+convert (fallback only) -------------
__global__ void transcvt(const float* __restrict__ in, ushort* __restrict__ out,
                         int R, int C) {
  __shared__ float tile[32 * 33];
  int e = blockIdx.z;
  const float* src = in + (size_t)e * R * C;
  ushort* dst = out + (size_t)e * R * C;
  int c0 = blockIdx.x * 32, r0 = blockIdx.y * 32;
  int lr = threadIdx.x >> 5, lc = threadIdx.x & 31;
#pragma unroll
  for (int p = 0; p < 4; ++p)
    tile[(p * 8 + lr) * 33 + lc] = src[(size_t)(r0 + p * 8 + lr) * C + c0 + lc];
  __syncthreads();
#pragma unroll
  for (int p = 0; p < 4; ++p)
    dst[(size_t)(c0 + p * 8 + lr) * R + r0 + lc] = f2bf(tile[lc * 33 + p * 8 + lr]);
}

// ---------------- prep: W1 transpose (blocks 0..32767) + router (rest) ----------------
__global__ void prep(const float* __restrict__ W1, ushort* __restrict__ W1T,
                     const float* __restrict__ x, const float* __restrict__ Wr,
                     const float* __restrict__ br, float* __restrict__ probs,
                     int* __restrict__ e_sel, float* __restrict__ w_sel,
                     ushort* __restrict__ xb) {
  __shared__ float shf[32 * 33];
  int b = blockIdx.x;
  if (b < 32768) {
    // transpose W1[e][d][f] -> W1T[e][f][d], 32x32 tile
    int cx = b & 127, ry = (b >> 7) & 31, e = b >> 12;
    const float* src = W1 + ((size_t)e * Dm + ry * 32) * Fm + cx * 32;
    int lr = threadIdx.x >> 5, lc = threadIdx.x & 31;
#pragma unroll
    for (int p = 0; p < 4; ++p)
      shf[(p * 8 + lr) * 33 + lc] = src[(size_t)(p * 8 + lr) * Fm + lc];
    __syncthreads();
#pragma unroll
    for (int p = 0; p < 4; ++p)
      W1T[((size_t)e * Fm + cx * 32 + p * 8 + lr) * Dm + ry * 32 + lc] =
          f2bf(shf[lc * 33 + p * 8 + lr]);
    return;
  }
  int t = b - 32768;
  const float4* xr4 = (const float4*)(x + (size_t)t * Dm);
  float4 v = xr4[threadIdx.x];
  ushort4 o;
  o.x = f2bf(v.x); o.y = f2bf(v.y); o.z = f2bf(v.z); o.w = f2bf(v.w);
  ((ushort4*)(xb + (size_t)t * Dm))[threadIdx.x] = o;

  int d0 = threadIdx.x * 4;
  const float4* wr4 = (const float4*)(Wr + (size_t)d0 * Em);
  float wv[4][8];
#pragma unroll
  for (int r = 0; r < 4; ++r) {
    float4 a = wr4[r * 2], bq = wr4[r * 2 + 1];
    wv[r][0] = a.x; wv[r][1] = a.y; wv[r][2] = a.z; wv[r][3] = a.w;
    wv[r][4] = bq.x; wv[r][5] = bq.y; wv[r][6] = bq.z; wv[r][7] = bq.w;
  }
  float xs[4] = {v.x, v.y, v.z, v.w};
  float acc[Em];
#pragma unroll
  for (int e = 0; e < Em; ++e)
    acc[e] = xs[0] * wv[0][e] + xs[1] * wv[1][e] + xs[2] * wv[2][e] + xs[3] * wv[3][e];
#pragma unroll
  for (int off = 32; off >= 1; off >>= 1)
#pragma unroll
    for (int e = 0; e < Em; ++e) acc[e] += __shfl_down(acc[e], off);
  float* red = shf;  // [4][8]
  int lane = threadIdx.x & 63, wid = threadIdx.x >> 6;
  if (lane == 0)
#pragma unroll
    for (int e = 0; e < Em; ++e) red[wid * 8 + e] = acc[e];
  __syncthreads();
  if (threadIdx.x == 0) {
    float lg[Em];
#pragma unroll
    for (int e = 0; e < Em; ++e)
      lg[e] = red[e] + red[8 + e] + red[16 + e] + red[24 + e] + br[e];
    int i0 = 0;
    for (int e = 1; e < Em; ++e) if (lg[e] > lg[i0]) i0 = e;
    int i1 = -1;
    for (int e = 0; e < Em; ++e) {
      if (e == i0) continue;
      if (i1 < 0 || lg[e] > lg[i1]) i1 = e;
    }
    float d = lg[i1] - lg[i0];
    float tt = expf(d);
    float inv = 1.f / (1.f + tt);
    probs[t * 2] = inv; probs[t * 2 + 1] = tt * inv;
    e_sel[t * 2] = i0; e_sel[t * 2 + 1] = i1;
    w_sel[t * 2] = inv; w_sel[t * 2 + 1] = tt * inv;
  }
}

// ---------------- build_lists (block 0) + out_init (blocks 1..2048) ----------------
__global__ void build2(const int* __restrict__ e_sel, const float* __restrict__ w_sel,
                       int* __restrict__ tok_of_row, float* __restrict__ w_of_row,
                       int* __restrict__ base, int* __restrict__ npad,
                       const float* __restrict__ b2, float* __restrict__ out) {
  int tid = threadIdx.x;
  if (blockIdx.x != 0) {
    int t = blockIdx.x - 1;
    int e0 = e_sel[2 * t], e1 = e_sel[2 * t + 1];
    float w0 = w_sel[2 * t], w1 = w_sel[2 * t + 1];
    const float4* p0 = (const float4*)(b2 + (size_t)e0 * Dm);
    const float4* p1 = (const float4*)(b2 + (size_t)e1 * Dm);
    float4* o = (float4*)(out + (size_t)t * Dm);
    float4 a = p0[tid], b = p1[tid];
    float4 r;
    r.x = w0 * a.x + w1 * b.x; r.y = w0 * a.y + w1 * b.y;
    r.z = w0 * a.z + w1 * b.z; r.w = w0 * a.w + w1 * b.w;
    o[tid] = r;
    return;
  }
  __shared__ int cnt[Em], run[Em], sbase[Em];
  __shared__ int wsum[4][Em];
  int lane = tid & 63, wid = tid >> 6;
  if (tid < Em) { cnt[tid] = 0; run[tid] = 0; }
  __syncthreads();
  for (int t = tid; t < TOKENS; t += 256) {
    atomicAdd(&cnt[e_sel[2 * t]], 1);
    atomicAdd(&cnt[e_sel[2 * t + 1]], 1);
  }
  __syncthreads();
  if (tid == 0) {
    int b = 0;
    for (int e = 0; e < Em; ++e) {
      base[e] = b; sbase[e] = b;
      int n = cnt[e];
      int p = (n + 127) & ~127;
      npad[e] = p; b += p;
    }
  }
  __syncthreads();
  for (int c = 0; c < TOKENS / 256; ++c) {
    int t = c * 256 + tid;
    int e0 = e_sel[2 * t], e1 = e_sel[2 * t + 1];
    unsigned long long mm[Em];
#pragma unroll
    for (int e = 0; e < Em; ++e) {
      unsigned long long m0 = __ballot(e0 == e);
      unsigned long long m1 = __ballot(e1 == e);
      mm[e] = m0 | m1;
      if (lane == 0) wsum[wid][e] = __popcll(mm[e]);
    }
    __syncthreads();
    unsigned long long below = (1ull << lane) - 1ull;
    {
      int e = e0;
      int p = __popcll(mm[e] & below);
      int pre = 0;
      for (int w = 0; w < wid; ++w) pre += wsum[w][e];
      int row = sbase[e] + run[e] + pre + p;
      tok_of_row[row] = t; w_of_row[row] = w_sel[2 * t];
    }
    {
      int e = e1;
      int p = __popcll(mm[e] & below);
      int pre = 0;
      for (int w = 0; w < wid; ++w) pre += wsum[w][e];
      int row = sbase[e] + run[e] + pre + p;
      tok_of_row[row] = t; w_of_row[row] = w_sel[2 * t + 1];
    }
    __syncthreads();
    if (tid < Em) {
      int s = 0;
      for (int w = 0; w < 4; ++w) s += wsum[w][tid];
      run[tid] += s;
    }
    __syncthreads();
  }
  for (int e = 0; e < Em; ++e) {
    int n = cnt[e];
    int p = (n + 127) & ~127;
    for (int i = n + tid; i < p; i += 256) {
      tok_of_row[sbase[e] + i] = -1;
      w_of_row[sbase[e] + i] = 0.f;
    }
  }
}

// ---------------- GEMM1 + hidden W2 transpose in idle blocks ----------------
// grid (x = n-tile [32], y = e*16+rt [128]); BK=64, XOR-swizzled LDS
__global__ __launch_bounds__(256) void gemm1(
    const ushort* __restrict__ xb, const ushort* __restrict__ W1T,
    const float* __restrict__ b1, ushort* __restrict__ H,
    const int* __restrict__ tok_of_row, const int* __restrict__ base,
    const int* __restrict__ npad,
    const float* __restrict__ W2, ushort* __restrict__ W2T, int do_w2) {
  __shared__ ushort sbuf[17408];  // staging: A 8192 + B 8192 elems; epilogue: 128x136
  __shared__ int toks[128];
  int tid = threadIdx.x, lane = tid & 63, wid = tid >> 6;
  int e = blockIdx.y >> 4, rt = blockIdx.y & 15;
  int nt = npad[e] >> 7;
  if (rt >= nt) {
    if (!do_w2) return;
    // -------- idle block: transpose W2[e2][f][d] -> W2T[e2][d][f] --------
    int act = 0, pre = 0;
#pragma unroll
    for (int e2 = 0; e2 < Em; ++e2) {
      int n2 = npad[e2] >> 7;
      act += n2;
      if (e2 < e) pre += 16 - n2;
    }
    int idle_id = (pre + rt - nt) * 32 + blockIdx.x;
    int total_idle = (128 - act) * 32;
    float* ft = (float*)sbuf;
    int lr = tid >> 5, lc = tid & 31;
    for (int t = idle_id; t < 32768; t += total_idle) {
      int x2 = t & 31, y2 = (t >> 5) & 127, e2 = t >> 12;
      const float* src = W2 + ((size_t)e2 * Fm + y2 * 32) * Dm + x2 * 32;
#pragma unroll
      for (int p = 0; p < 4; ++p)
        ft[(p * 8 + lr) * 33 + lc] = src[(size_t)(p * 8 + lr) * Dm + lc];
      __syncthreads();
#pragma unroll
      for (int p = 0; p < 4; ++p)
        W2T[((size_t)e2 * Dm + x2 * 32 + p * 8 + lr) * Fm + y2 * 32 + lc] =
            f2bf(ft[lc * 33 + p * 8 + lr]);
      __syncthreads();
    }
    return;
  }
  // -------- active block --------
  int row0 = base[e] + rt * 128;
  int n0 = blockIdx.x * 128;
  if (tid < 128) toks[tid] = tok_of_row[row0 + tid];
  __syncthreads();
  ushort* As = sbuf;
  ushort* Bs = sbuf + 8192;
  int sub = tid & 7, rl0 = tid >> 3;
  const ushort *pa0, *pa1, *pa2, *pa3, *pb0, *pb1, *pb2, *pb3;
#define MKPTR1(c, pa, pb) {                                                 \
    int row = (c) * 32 + rl0; int r7 = row & 7;                             \
    int tk = toks[row]; if (tk < 0) tk = 0;                                 \
    int so = (sub ^ r7) << 3;                                               \
    pa = xb + (size_t)tk * Dm + so;                                         \
    pb = W1T + ((size_t)e * Fm + n0 + row) * Dm + so; }
  MKPTR1(0, pa0, pb0)
  MKPTR1(1, pa1, pb1)
  MKPTR1(2, pa2, pb2)
  MKPTR1(3, pa3, pb3)
  char* la = (char*)sbuf + wid * 1024;
  char* lb = (char*)sbuf + 16384 + wid * 1024;
  int wr2 = wid >> 1, wc2 = wid & 1;
  int g = lane >> 4, l7 = lane & 7;
  int aidx = (wr2 * 64 + (lane & 15)) * 64 + ((g ^ l7) << 3);
  int bidx = (wc2 * 64 + (lane & 15)) * 64 + ((g ^ l7) << 3);
  f32x4 acc[4][4] = {};
  for (int kt = 0; kt < Dm / 64; ++kt) {
    GLOAD16(pa0, la);
    GLOAD16(pa1, la + 4096);
    GLOAD16(pa2, la + 8192);
    GLOAD16(pa3, la + 12288);
    GLOAD16(pb0, lb);
    GLOAD16(pb1, lb + 4096);
    GLOAD16(pb2, lb + 8192);
    GLOAD16(pb3, lb + 12288);
    pa0 += 64; pa1 += 64; pa2 += 64; pa3 += 64;
    pb0 += 64; pb1 += 64; pb2 += 64; pb3 += 64;
    __syncthreads();
#pragma unroll
    for (int kk = 0; kk < 2; ++kk) {
      s16x8 av[4], bv[4];
#pragma unroll
      for (int m = 0; m < 4; ++m)
        av[m] = *(const s16x8*)(As + ((aidx + m * 1024) ^ (kk << 5)));
#pragma unroll
      for (int n = 0; n < 4; ++n)
        bv[n] = *(const s16x8*)(Bs + ((bidx + n * 1024) ^ (kk << 5)));
#pragma unroll
      for (int m = 0; m < 4; ++m)
#pragma unroll
        for (int n = 0; n < 4; ++n)
          acc[m][n] = __builtin_amdgcn_mfma_f32_16x16x32_bf16(av[m], bv[n], acc[m][n], 0, 0, 0);
    }
    __syncthreads();
  }
  // -------- epilogue: gelu -> LDS C-tile -> coalesced stores --------
  int crow = wr2 * 64 + g * 4;
  int ccol = wc2 * 64 + (lane & 15);
#pragma unroll
  for (int n = 0; n < 4; ++n) {
    int col = n0 + ccol + n * 16;
    float bias = b1[e * Fm + col];
#pragma unroll
    for (int m = 0; m < 4; ++m) {
#pragma unroll
      for (int j = 0; j < 4; ++j) {
        float v = acc[m][n][j] + bias;
        float gl = 0.5f * v * (1.f + erff(v * 0.70710678118654752f));
        sbuf[(crow + m * 16 + j) * 136 + ccol + n * 16] = f2bf(gl);
      }
    }
  }
  __syncthreads();
#pragma unroll
  for (int q = 0; q < 8; ++q) {
    int id = q * 256 + tid;
    int r = id >> 4, ch = id & 15;
    s16x8 vv = *(const s16x8*)(sbuf + r * 136 + ch * 8);
    *(s16x8*)(H + (size_t)(row0 + r) * Fm + n0 + ch * 8) = vv;
  }
}

// ---------------- GEMM2: out[tok] += w * (H @ W2T^T); BK=64, swizzled ----------------
// grid (x = n-tile [8], y = e*16+rt [128], z = k-half [2])
__global__ __launch_bounds__(256) void gemm2(
    const ushort* __restrict__ H, const ushort* __restrict__ W2T,
    const int* __restrict__ tok_of_row, const float* __restrict__ w_of_row,
    const int* __restrict__ base, const int* __restrict__ npad,
    float* __restrict__ out) {
  __shared__ ushort sbuf[16384];
  __shared__ int toks[128];
  __shared__ float wts[128];
  int tid = threadIdx.x, lane = tid & 63, wid = tid >> 6;
  int e = blockIdx.y >> 4, rt = blockIdx.y & 15;
  int nt = npad[e] >> 7;
  if (rt >= nt) return;
  int row0 = base[e] + rt * 128;
  int n0 = blockIdx.x * 128;
  int k0 = blockIdx.z * (Fm / 2);
  if (tid < 128) {
    toks[tid] = tok_of_row[row0 + tid];
    wts[tid] = w_of_row[row0 + tid];
  }
  __syncthreads();
  ushort* As = sbuf;
  ushort* Bs = sbuf + 8192;
  int sub = tid & 7, rl0 = tid >> 3;
  const ushort *pa0, *pa1, *pa2, *pa3, *pb0, *pb1, *pb2, *pb3;
#define MKPTR2(c, pa, pb) {                                                 \
    int row = (c) * 32 + rl0; int r7 = row & 7;                             \
    int so = (sub ^ r7) << 3;                                               \
    pa = H + (size_t)(row0 + row) * Fm + k0 + so;                           \
    pb = W2T + ((size_t)e * Dm + n0 + row) * Fm + k0 + so; }
  MKPTR2(0, pa0, pb0)
  MKPTR2(1, pa1, pb1)
  MKPTR2(2, pa2, pb2)
  MKPTR2(3, pa3, pb3)
  char* la = (char*)sbuf + wid * 1024;
  char* lb = (char*)sbuf + 16384 + wid * 1024;
  int wr2 = wid >> 1, wc2 = wid & 1;
  int g = lane >> 4, l7 = lane & 7;
  int aidx = (wr2 * 64 + (lane & 15)) * 64 + ((g ^ l7) << 3);
  int bidx = (wc2 * 64 + (lane & 15)) * 64 + ((g ^ l7) << 3);
  f32x4 acc[4][4] = {};
  for (int kt = 0; kt < Fm / 2 / 64; ++kt) {
    GLOAD16(pa0, la);
    GLOAD16(pa1, la + 4096);
    GLOAD16(pa2, la + 8192);
    GLOAD16(pa3, la + 12288);
    GLOAD16(pb0, lb);
    GLOAD16(pb1, lb + 4096);
    GLOAD16(pb2, lb + 8192);
    GLOAD16(pb3, lb + 12288);
    pa0 += 64; pa1 += 64; pa2 += 64; pa3 += 64;
    pb0 += 64; pb1 += 64; pb2 += 64; pb3 += 64;
    __syncthreads();
#pragma unroll
    for (int kk = 0; kk < 2; ++kk) {
      s16x8 av[4], bv[4];
#pragma unroll
      for (int m = 0; m < 4; ++m)
        av[m] = *(const s16x8*)(As + ((aidx + m * 1024) ^ (kk << 5)));
#pragma unroll
      for (int n = 0; n < 4; ++n)
        bv[n] = *(const s16x8*)(Bs + ((bidx + n * 1024) ^ (kk << 5)));
#pragma unroll
      for (int m = 0; m < 4; ++m)
#pragma unroll
        for (int n = 0; n < 4; ++n)
          acc[m][n] = __builtin_amdgcn_mfma_f32_16x16x32_bf16(av[m], bv[n], acc[m][n], 0, 0, 0);
    }
    __syncthreads();
  }
  int rb = wr2 * 64 + g * 4;
  int cb = n0 + wc2 * 64 + (lane & 15);
#pragma unroll
  for (int n = 0; n < 4; ++n) {
    int col = cb + n * 16;
#pragma unroll
    for (int m = 0; m < 4; ++m) {
      int rl = rb + m * 16;
#pragma unroll
      for (int j = 0; j < 4; ++j) {
        int tok = toks[rl + j];
        if (tok >= 0)
          atomicAdd(&out[(size_t)tok * Dm + col], wts[rl + j] * acc[m][n][j]);
      }
    }
  }
}

extern "C" void kernel_launch(void* const* d_in, const int* in_sizes, int n_in,
                              void* d_out, int out_size, void* d_ws, size_t ws_size,
                              hipStream_t stream) {
  const float* x  = (const float*)d_in[0];
  const float* Wr = (const float*)d_in[1];
  const float* br = (const float*)d_in[2];
  const float* W1 = (const float*)d_in[3];
  const float* b1 = (const float*)d_in[4];
  const float* W2 = (const float*)d_in[5];
  const float* b2 = (const float*)d_in[6];
  float* out = (float*)d_out;
  float* probs = out + (size_t)TOKENS * Dm;

  char* ws = (char*)d_ws;
  ushort* W1T  = (ushort*)ws;                          // 67,108,864 B
  ushort* Hbuf = (ushort*)(ws + 67108864);             // 41,943,040 B (5120 rows)
  ushort* xb   = (ushort*)(ws + 109051904);            //  4,194,304 B
  int*   tok_of_row = (int*)(ws + 113246208);          // 20,480 B
  float* w_of_row   = (float*)(ws + 113266688);        // 20,480 B
  int*   e_sel      = (int*)(ws + 113287168);          // 16,384 B
  float* w_sel      = (float*)(ws + 113303552);        // 16,384 B
  int*   meta       = (int*)(ws + 113319936);          // base[8], npad[8]
  // separate W2T buffer if scratch allows; else reuse W1T region (serial pass)
  int sep = (ws_size >= 180429056ULL) ? 1 : 0;
  ushort* W2T = sep ? (ushort*)(ws + 113320192) : W1T;

  prep<<<32768 + TOKENS, 256, 0, stream>>>(W1, W1T, x, Wr, br, probs, e_sel, w_sel, xb);
  build2<<<TOKENS + 1, 256, 0, stream>>>(e_sel, w_sel, tok_of_row, w_of_row,
                                         meta, meta + 8, b2, out);
  gemm1<<<dim3(32, 128), 256, 0, stream>>>(xb, W1T, b1, Hbuf, tok_of_row,
                                           meta, meta + 8, W2, W2T, sep);
  if (!sep)
    transcvt<<<dim3(Dm / 32, Fm / 32, Em), 256, 0, stream>>>(W2, W2T, Fm, Dm);
  gemm2<<<dim3(8, 128, 2), 256, 0, stream>>>(Hbuf, W2T, tok_of_row, w_of_row,
                                             meta, meta + 8, out);
}

// Round 4
// 303.826 us; speedup vs baseline: 1.0326x; 1.0326x over previous
//
#include <hip/hip_runtime.h>
#include <hip/hip_bf16.h>
#include <cstdint>

#define TOKENS 2048
#define Dm 1024
#define Fm 4096
#define Em 8

typedef short s16x8 __attribute__((ext_vector_type(8)));
typedef float f32x4 __attribute__((ext_vector_type(4)));

#define GLOAD16(g, l) __builtin_amdgcn_global_load_lds(                     \
    (const __attribute__((address_space(1))) void*)(g),                     \
    (__attribute__((address_space(3))) void*)(l), 16, 0, 0)

__device__ __forceinline__ ushort f2bf(float f) {
  union { float f; uint32_t u; } v; v.f = f;
  uint32_t r = v.u + 0x7fffu + ((v.u >> 16) & 1u);
  return (ushort)(r >> 16);
}

// ------------- standalone transpose+convert (fallback only) -------------
__global__ void transcvt(const float* __restrict__ in, ushort* __restrict__ out,
                         int R, int C) {
  __shared__ float tile[32 * 33];
  int e = blockIdx.z;
  const float* src = in + (size_t)e * R * C;
  ushort* dst = out + (size_t)e * R * C;
  int c0 = blockIdx.x * 32, r0 = blockIdx.y * 32;
  int lr = threadIdx.x >> 5, lc = threadIdx.x & 31;
#pragma unroll
  for (int p = 0; p < 4; ++p)
    tile[(p * 8 + lr) * 33 + lc] = src[(size_t)(r0 + p * 8 + lr) * C + c0 + lc];
  __syncthreads();
#pragma unroll
  for (int p = 0; p < 4; ++p)
    dst[(size_t)(c0 + p * 8 + lr) * R + r0 + lc] = f2bf(tile[lc * 33 + p * 8 + lr]);
}

// ---------------- prep: W1 transpose (blocks 0..32767) + router (rest) ----------------
__global__ void prep(const float* __restrict__ W1, ushort* __restrict__ W1T,
                     const float* __restrict__ x, const float* __restrict__ Wr,
                     const float* __restrict__ br, float* __restrict__ probs,
                     int* __restrict__ e_sel, float* __restrict__ w_sel,
                     ushort* __restrict__ xb) {
  __shared__ float shf[32 * 33];
  int b = blockIdx.x;
  if (b < 32768) {
    int cx = b & 127, ry = (b >> 7) & 31, e = b >> 12;
    const float* src = W1 + ((size_t)e * Dm + ry * 32) * Fm + cx * 32;
    int lr = threadIdx.x >> 5, lc = threadIdx.x & 31;
#pragma unroll
    for (int p = 0; p < 4; ++p)
      shf[(p * 8 + lr) * 33 + lc] = src[(size_t)(p * 8 + lr) * Fm + lc];
    __syncthreads();
#pragma unroll
    for (int p = 0; p < 4; ++p)
      W1T[((size_t)e * Fm + cx * 32 + p * 8 + lr) * Dm + ry * 32 + lc] =
          f2bf(shf[lc * 33 + p * 8 + lr]);
    return;
  }
  int t = b - 32768;
  const float4* xr4 = (const float4*)(x + (size_t)t * Dm);
  float4 v = xr4[threadIdx.x];
  ushort4 o;
  o.x = f2bf(v.x); o.y = f2bf(v.y); o.z = f2bf(v.z); o.w = f2bf(v.w);
  ((ushort4*)(xb + (size_t)t * Dm))[threadIdx.x] = o;

  int d0 = threadIdx.x * 4;
  const float4* wr4 = (const float4*)(Wr + (size_t)d0 * Em);
  float wv[4][8];
#pragma unroll
  for (int r = 0; r < 4; ++r) {
    float4 a = wr4[r * 2], bq = wr4[r * 2 + 1];
    wv[r][0] = a.x; wv[r][1] = a.y; wv[r][2] = a.z; wv[r][3] = a.w;
    wv[r][4] = bq.x; wv[r][5] = bq.y; wv[r][6] = bq.z; wv[r][7] = bq.w;
  }
  float xs[4] = {v.x, v.y, v.z, v.w};
  float acc[Em];
#pragma unroll
  for (int e = 0; e < Em; ++e)
    acc[e] = xs[0] * wv[0][e] + xs[1] * wv[1][e] + xs[2] * wv[2][e] + xs[3] * wv[3][e];
#pragma unroll
  for (int off = 32; off >= 1; off >>= 1)
#pragma unroll
    for (int e = 0; e < Em; ++e) acc[e] += __shfl_down(acc[e], off);
  float* red = shf;
  int lane = threadIdx.x & 63, wid = threadIdx.x >> 6;
  if (lane == 0)
#pragma unroll
    for (int e = 0; e < Em; ++e) red[wid * 8 + e] = acc[e];
  __syncthreads();
  if (threadIdx.x == 0) {
    float lg[Em];
#pragma unroll
    for (int e = 0; e < Em; ++e)
      lg[e] = red[e] + red[8 + e] + red[16 + e] + red[24 + e] + br[e];
    int i0 = 0;
    for (int e = 1; e < Em; ++e) if (lg[e] > lg[i0]) i0 = e;
    int i1 = -1;
    for (int e = 0; e < Em; ++e) {
      if (e == i0) continue;
      if (i1 < 0 || lg[e] > lg[i1]) i1 = e;
    }
    float d = lg[i1] - lg[i0];
    float tt = expf(d);
    float inv = 1.f / (1.f + tt);
    probs[t * 2] = inv; probs[t * 2 + 1] = tt * inv;
    e_sel[t * 2] = i0; e_sel[t * 2 + 1] = i1;
    w_sel[t * 2] = inv; w_sel[t * 2 + 1] = tt * inv;
  }
}

// ---------------- build_lists (block 0) + out_init (blocks 1..2048) ----------------
__global__ void build2(const int* __restrict__ e_sel, const float* __restrict__ w_sel,
                       int* __restrict__ tok_of_row, float* __restrict__ w_of_row,
                       int* __restrict__ base, int* __restrict__ npad,
                       const float* __restrict__ b2, float* __restrict__ out) {
  int tid = threadIdx.x;
  if (blockIdx.x != 0) {
    int t = blockIdx.x - 1;
    int e0 = e_sel[2 * t], e1 = e_sel[2 * t + 1];
    float w0 = w_sel[2 * t], w1 = w_sel[2 * t + 1];
    const float4* p0 = (const float4*)(b2 + (size_t)e0 * Dm);
    const float4* p1 = (const float4*)(b2 + (size_t)e1 * Dm);
    float4* o = (float4*)(out + (size_t)t * Dm);
    float4 a = p0[tid], b = p1[tid];
    float4 r;
    r.x = w0 * a.x + w1 * b.x; r.y = w0 * a.y + w1 * b.y;
    r.z = w0 * a.z + w1 * b.z; r.w = w0 * a.w + w1 * b.w;
    o[tid] = r;
    return;
  }
  __shared__ int cnt[Em], run[Em], sbase[Em];
  __shared__ int wsum[4][Em];
  int lane = tid & 63, wid = tid >> 6;
  if (tid < Em) { cnt[tid] = 0; run[tid] = 0; }
  __syncthreads();
  for (int t = tid; t < TOKENS; t += 256) {
    atomicAdd(&cnt[e_sel[2 * t]], 1);
    atomicAdd(&cnt[e_sel[2 * t + 1]], 1);
  }
  __syncthreads();
  if (tid == 0) {
    int b = 0;
    for (int e = 0; e < Em; ++e) {
      base[e] = b; sbase[e] = b;
      int n = cnt[e];
      int p = (n + 127) & ~127;
      npad[e] = p; b += p;
    }
  }
  __syncthreads();
  for (int c = 0; c < TOKENS / 256; ++c) {
    int t = c * 256 + tid;
    int e0 = e_sel[2 * t], e1 = e_sel[2 * t + 1];
    unsigned long long mm[Em];
#pragma unroll
    for (int e = 0; e < Em; ++e) {
      unsigned long long m0 = __ballot(e0 == e);
      unsigned long long m1 = __ballot(e1 == e);
      mm[e] = m0 | m1;
      if (lane == 0) wsum[wid][e] = __popcll(mm[e]);
    }
    __syncthreads();
    unsigned long long below = (1ull << lane) - 1ull;
    {
      int e = e0;
      int p = __popcll(mm[e] & below);
      int pre = 0;
      for (int w = 0; w < wid; ++w) pre += wsum[w][e];
      int row = sbase[e] + run[e] + pre + p;
      tok_of_row[row] = t; w_of_row[row] = w_sel[2 * t];
    }
    {
      int e = e1;
      int p = __popcll(mm[e] & below);
      int pre = 0;
      for (int w = 0; w < wid; ++w) pre += wsum[w][e];
      int row = sbase[e] + run[e] + pre + p;
      tok_of_row[row] = t; w_of_row[row] = w_sel[2 * t + 1];
    }
    __syncthreads();
    if (tid < Em) {
      int s = 0;
      for (int w = 0; w < 4; ++w) s += wsum[w][tid];
      run[tid] += s;
    }
    __syncthreads();
  }
  for (int e = 0; e < Em; ++e) {
    int n = cnt[e];
    int p = (n + 127) & ~127;
    for (int i = n + tid; i < p; i += 256) {
      tok_of_row[sbase[e] + i] = -1;
      w_of_row[sbase[e] + i] = 0.f;
    }
  }
}

// ---------------- GEMM1 (BK=32, 16.9KB LDS) + hidden W2 transpose ----------------
// grid (x = n-tile [32], y = e*16+rt [128])
__global__ __launch_bounds__(256) void gemm1(
    const ushort* __restrict__ xb, const ushort* __restrict__ W1T,
    const float* __restrict__ b1, ushort* __restrict__ H,
    const int* __restrict__ tok_of_row, const int* __restrict__ base,
    const int* __restrict__ npad,
    const float* __restrict__ W2, ushort* __restrict__ W2T, int do_w2) {
  __shared__ ushort sbuf[8192];   // A 4096 + B 4096; epilogue reuse as [64][128]
  __shared__ int toks[128];
  int tid = threadIdx.x, lane = tid & 63, wid = tid >> 6;
  int e = blockIdx.y >> 4, rt = blockIdx.y & 15;
  int nt = npad[e] >> 7;
  if (rt >= nt) {
    if (!do_w2) return;
    // idle block: transpose W2[e2][f][d] -> W2T[e2][d][f]
    int act = 0, pre = 0;
#pragma unroll
    for (int e2 = 0; e2 < Em; ++e2) {
      int n2 = npad[e2] >> 7;
      act += n2;
      if (e2 < e) pre += 16 - n2;
    }
    int idle_id = (pre + rt - nt) * 32 + blockIdx.x;
    int total_idle = (128 - act) * 32;
    float* ft = (float*)sbuf;
    int lr = tid >> 5, lc = tid & 31;
    for (int t = idle_id; t < 32768; t += total_idle) {
      int x2 = t & 31, y2 = (t >> 5) & 127, e2 = t >> 12;
      const float* src = W2 + ((size_t)e2 * Fm + y2 * 32) * Dm + x2 * 32;
#pragma unroll
      for (int p = 0; p < 4; ++p)
        ft[(p * 8 + lr) * 33 + lc] = src[(size_t)(p * 8 + lr) * Dm + lc];
      __syncthreads();
#pragma unroll
      for (int p = 0; p < 4; ++p)
        W2T[((size_t)e2 * Dm + x2 * 32 + p * 8 + lr) * Fm + y2 * 32 + lc] =
            f2bf(ft[lc * 33 + p * 8 + lr]);
      __syncthreads();
    }
    return;
  }
  int row0 = base[e] + rt * 128;
  int n0 = blockIdx.x * 128;
  if (tid < 128) toks[tid] = tok_of_row[row0 + tid];
  __syncthreads();
  ushort* As = sbuf;
  ushort* Bs = sbuf + 4096;
  // staging: arow 0..63 (+64 for second gload), 4 chunks of 8 elems per 32-k row
  int arow = tid >> 2, asub = tid & 3;
  int sw = ((asub ^ ((arow >> 1) & 3)) << 3);   // XOR-swizzled chunk (write side)
  int t0 = toks[arow];      if (t0 < 0) t0 = 0;
  int t1 = toks[64 + arow]; if (t1 < 0) t1 = 0;
  const ushort* sA0 = xb + (size_t)t0 * Dm + sw;
  const ushort* sA1 = xb + (size_t)t1 * Dm + sw;
  const ushort* sB0 = W1T + ((size_t)e * Fm + n0 + arow) * Dm + sw;
  const ushort* sB1 = sB0 + (size_t)64 * Dm;
  char* ldA0 = (char*)As + wid * 1024;
  char* ldA1 = (char*)As + 4096 + wid * 1024;
  char* ldB0 = (char*)Bs + wid * 1024;
  char* ldB1 = (char*)Bs + 4096 + wid * 1024;
  int wr2 = wid >> 1, wc2 = wid & 1;
  int g = lane >> 4, c = (lane >> 1) & 3;       // read-side XOR
  int aidx = (wr2 * 64 + (lane & 15)) * 32 + ((g ^ c) << 3);
  int bidx = (wc2 * 64 + (lane & 15)) * 32 + ((g ^ c) << 3);
  f32x4 acc[4][4] = {};
  for (int kt = 0; kt < Dm / 32; ++kt) {
    GLOAD16(sA0, ldA0);
    GLOAD16(sA1, ldA1);
    GLOAD16(sB0, ldB0);
    GLOAD16(sB1, ldB1);
    sA0 += 32; sA1 += 32; sB0 += 32; sB1 += 32;
    __syncthreads();
    s16x8 av[4], bv[4];
#pragma unroll
    for (int m = 0; m < 4; ++m) av[m] = *(const s16x8*)(As + aidx + m * 512);
#pragma unroll
    for (int n = 0; n < 4; ++n) bv[n] = *(const s16x8*)(Bs + bidx + n * 512);
#pragma unroll
    for (int m = 0; m < 4; ++m)
#pragma unroll
      for (int n = 0; n < 4; ++n)
        acc[m][n] = __builtin_amdgcn_mfma_f32_16x16x32_bf16(av[m], bv[n], acc[m][n], 0, 0, 0);
    __syncthreads();
  }
  // epilogue: gelu -> 2-pass LDS staging (64x128) -> coalesced dwordx4 stores
#pragma unroll
  for (int p = 0; p < 2; ++p) {
    if (wr2 == p) {
#pragma unroll
      for (int n = 0; n < 4; ++n) {
        int col = wc2 * 64 + (lane & 15) + n * 16;
        float bias = b1[e * Fm + n0 + col];
#pragma unroll
        for (int m = 0; m < 4; ++m) {
#pragma unroll
          for (int j = 0; j < 4; ++j) {
            float v = acc[m][n][j] + bias;
            float gl = 0.5f * v * (1.f + erff(v * 0.70710678118654752f));
            sbuf[(g * 4 + m * 16 + j) * 128 + col] = f2bf(gl);
          }
        }
      }
    }
    __syncthreads();
#pragma unroll
    for (int q = 0; q < 4; ++q) {
      int id = q * 256 + tid;
      int r = id >> 4, ch = id & 15;
      *(s16x8*)(H + (size_t)(row0 + p * 64 + r) * Fm + n0 + ch * 8) =
          *(const s16x8*)(sbuf + r * 128 + ch * 8);
    }
    __syncthreads();
  }
}

// ---------------- GEMM2: out[tok] += w * (H @ W2T^T); BK=32, swizzled ----------------
// grid (x = n-tile [8], y = e*16+rt [128], z = k-half [2])
__global__ __launch_bounds__(256) void gemm2(
    const ushort* __restrict__ H, const ushort* __restrict__ W2T,
    const int* __restrict__ tok_of_row, const float* __restrict__ w_of_row,
    const int* __restrict__ base, const int* __restrict__ npad,
    float* __restrict__ out) {
  __shared__ ushort sbuf[8192];
  __shared__ int toks[128];
  __shared__ float wts[128];
  int tid = threadIdx.x, lane = tid & 63, wid = tid >> 6;
  int e = blockIdx.y >> 4, rt = blockIdx.y & 15;
  int nt = npad[e] >> 7;
  if (rt >= nt) return;
  int row0 = base[e] + rt * 128;
  int n0 = blockIdx.x * 128;
  int k0 = blockIdx.z * (Fm / 2);
  if (tid < 128) {
    toks[tid] = tok_of_row[row0 + tid];
    wts[tid] = w_of_row[row0 + tid];
  }
  __syncthreads();
  ushort* As = sbuf;
  ushort* Bs = sbuf + 4096;
  int arow = tid >> 2, asub = tid & 3;
  int sw = ((asub ^ ((arow >> 1) & 3)) << 3);
  const ushort* sA0 = H + (size_t)(row0 + arow) * Fm + k0 + sw;
  const ushort* sA1 = sA0 + (size_t)64 * Fm;
  const ushort* sB0 = W2T + ((size_t)e * Dm + n0 + arow) * Fm + k0 + sw;
  const ushort* sB1 = sB0 + (size_t)64 * Fm;
  char* ldA0 = (char*)As + wid * 1024;
  char* ldA1 = (char*)As + 4096 + wid * 1024;
  char* ldB0 = (char*)Bs + wid * 1024;
  char* ldB1 = (char*)Bs + 4096 + wid * 1024;
  int wr2 = wid >> 1, wc2 = wid & 1;
  int g = lane >> 4, c = (lane >> 1) & 3;
  int aidx = (wr2 * 64 + (lane & 15)) * 32 + ((g ^ c) << 3);
  int bidx = (wc2 * 64 + (lane & 15)) * 32 + ((g ^ c) << 3);
  f32x4 acc[4][4] = {};
  for (int kt = 0; kt < Fm / 2 / 32; ++kt) {
    GLOAD16(sA0, ldA0);
    GLOAD16(sA1, ldA1);
    GLOAD16(sB0, ldB0);
    GLOAD16(sB1, ldB1);
    sA0 += 32; sA1 += 32; sB0 += 32; sB1 += 32;
    __syncthreads();
    s16x8 av[4], bv[4];
#pragma unroll
    for (int m = 0; m < 4; ++m) av[m] = *(const s16x8*)(As + aidx + m * 512);
#pragma unroll
    for (int n = 0; n < 4; ++n) bv[n] = *(const s16x8*)(Bs + bidx + n * 512);
#pragma unroll
    for (int m = 0; m < 4; ++m)
#pragma unroll
      for (int n = 0; n < 4; ++n)
        acc[m][n] = __builtin_amdgcn_mfma_f32_16x16x32_bf16(av[m], bv[n], acc[m][n], 0, 0, 0);
    __syncthreads();
  }
  int rb = wr2 * 64 + g * 4;
  int cb = n0 + wc2 * 64 + (lane & 15);
#pragma unroll
  for (int n = 0; n < 4; ++n) {
    int col = cb + n * 16;
#pragma unroll
    for (int m = 0; m < 4; ++m) {
      int rl = rb + m * 16;
#pragma unroll
      for (int j = 0; j < 4; ++j) {
        int tok = toks[rl + j];
        if (tok >= 0)
          atomicAdd(&out[(size_t)tok * Dm + col], wts[rl + j] * acc[m][n][j]);
      }
    }
  }
}

extern "C" void kernel_launch(void* const* d_in, const int* in_sizes, int n_in,
                              void* d_out, int out_size, void* d_ws, size_t ws_size,
                              hipStream_t stream) {
  const float* x  = (const float*)d_in[0];
  const float* Wr = (const float*)d_in[1];
  const float* br = (const float*)d_in[2];
  const float* W1 = (const float*)d_in[3];
  const float* b1 = (const float*)d_in[4];
  const float* W2 = (const float*)d_in[5];
  const float* b2 = (const float*)d_in[6];
  float* out = (float*)d_out;
  float* probs = out + (size_t)TOKENS * Dm;

  char* ws = (char*)d_ws;
  ushort* W1T  = (ushort*)ws;                          // 67,108,864 B
  ushort* Hbuf = (ushort*)(ws + 67108864);             // 41,943,040 B (5120 rows)
  ushort* xb   = (ushort*)(ws + 109051904);            //  4,194,304 B
  int*   tok_of_row = (int*)(ws + 113246208);
  float* w_of_row   = (float*)(ws + 113266688);
  int*   e_sel      = (int*)(ws + 113287168);
  float* w_sel      = (float*)(ws + 113303552);
  int*   meta       = (int*)(ws + 113319936);          // base[8], npad[8]
  int sep = (ws_size >= 180429056ULL) ? 1 : 0;
  ushort* W2T = sep ? (ushort*)(ws + 113320192) : W1T;

  prep<<<32768 + TOKENS, 256, 0, stream>>>(W1, W1T, x, Wr, br, probs, e_sel, w_sel, xb);
  build2<<<TOKENS + 1, 256, 0, stream>>>(e_sel, w_sel, tok_of_row, w_of_row,
                                         meta, meta + 8, b2, out);
  gemm1<<<dim3(32, 128), 256, 0, stream>>>(xb, W1T, b1, Hbuf, tok_of_row,
                                           meta, meta + 8, W2, W2T, sep);
  if (!sep)
    transcvt<<<dim3(Dm / 32, Fm / 32, Em), 256, 0, stream>>>(W2, W2T, Fm, Dm);
  gemm2<<<dim3(8, 128, 2), 256, 0, stream>>>(Hbuf, W2T, tok_of_row, w_of_row,
                                             meta, meta + 8, out);
}